// Round 11
// baseline (116.921 us; speedup 1.0000x reference)
//
#include <hip/hip_runtime.h>
#include <hip/hip_bf16.h>

#define HID 1024
#define MROWS 16384  // B*S = 4*4096

typedef __bf16 bf16;
typedef __bf16 bf16x8 __attribute__((ext_vector_type(8)));
typedef float f32x4 __attribute__((ext_vector_type(4)));

#define MFMA(va, vb, vc) __builtin_amdgcn_mfma_f32_16x16x32_bf16(va, vb, vc, 0, 0, 0)

// ---------------------------------------------------------------------------
// statswt_k: one launch, 2304 blocks x 256 thr.
//   blocks 0..255    : fold cos-FFT into W -> Wt (proven body)
//   blocks 256..2303 : row stats ONLY (mean, rstd) -> float2 stats[16384].
//                      Wave-per-row, no LDS/barriers (r8 structure minus
//                      the sin/A-write: 64 MB read, 128 KB written).
// ---------------------------------------------------------------------------
__global__ __launch_bounds__(256) void statswt_k(const float* __restrict__ x,
                                                 const float* __restrict__ W,
                                                 float2* __restrict__ stats,
                                                 bf16* __restrict__ Wt) {
    const int bid = blockIdx.x;
    const int t = threadIdx.x;

    if (bid < 256) {
        // ---- weight fold: Wt[n][q*64+d] = sum_qp ct[(q*qp)&15] * W[qp*64+d][n]
        const int idx = bid * 256 + t;  // 0..65535
        const int n = idx >> 6;
        const int d = idx & 63;

        float wv[16];
#pragma unroll
        for (int qp = 0; qp < 16; ++qp)
            wv[qp] = W[(size_t)(qp * 64 + d) * HID + n];

        const float ct[16] = {
            1.0f,  0.92387953f,  0.70710678f,  0.38268343f,
            0.0f, -0.38268343f, -0.70710678f, -0.92387953f,
           -1.0f, -0.92387953f, -0.70710678f, -0.38268343f,
            0.0f,  0.38268343f,  0.70710678f,  0.92387953f};

#pragma unroll
        for (int q = 0; q < 16; ++q) {
            float acc = 0.0f;
#pragma unroll
            for (int qp = 0; qp < 16; ++qp) acc += wv[qp] * ct[(q * qp) & 15];
            Wt[(size_t)n * HID + q * 64 + d] = (bf16)acc;
        }
        return;
    }

    // ---- stats: block p rows [p*8, p*8+8); wave w rows p*8 + rr*4 + w
    const int p = bid - 256;
    const int w = t >> 6, ln = t & 63;
    const int c0 = ln * 8;

#pragma unroll
    for (int rr = 0; rr < 2; ++rr) {
        const int row = p * 8 + rr * 4 + w;
        const float* xr = x + (size_t)row * HID;

        float4 v0 = *(const float4*)&xr[c0];
        float4 v1 = *(const float4*)&xr[c0 + 4];
        float4 v2 = *(const float4*)&xr[512 + c0];
        float4 v3 = *(const float4*)&xr[512 + c0 + 4];

        float s = v0.x + v0.y + v0.z + v0.w + v1.x + v1.y + v1.z + v1.w +
                  v2.x + v2.y + v2.z + v2.w + v3.x + v3.y + v3.z + v3.w;
        float ss = v0.x * v0.x + v0.y * v0.y + v0.z * v0.z + v0.w * v0.w +
                   v1.x * v1.x + v1.y * v1.y + v1.z * v1.z + v1.w * v1.w +
                   v2.x * v2.x + v2.y * v2.y + v2.z * v2.z + v2.w * v2.w +
                   v3.x * v3.x + v3.y * v3.y + v3.z * v3.z + v3.w * v3.w;
#pragma unroll
        for (int off = 32; off; off >>= 1) {
            s  += __shfl_xor(s, off);
            ss += __shfl_xor(ss, off);
        }
        const float mean = s * (1.0f / HID);
        const float rstd = rsqrtf(ss * (1.0f / HID) - mean * mean + 1e-6f);
        if (ln == 0) stats[row] = make_float2(mean, rstd);
    }
}

// ---------------------------------------------------------------------------
// Fused GEMM: C[m][n] = sum_k (0.5 sin(2 LN(x)))[m][k] * Wt[n][k] + bias[n]
// Proven 256x256 8-phase skeleton. A is computed in-block: P0 issues the
// next tile's x-loads (f32, L3-hot); P3 drains vmcnt(0) (all vmem >=1 phase
// old, B is L2-resident), applies LN+sin using LDS-cached stats/gamma/beta,
// and ds_writes the SAME XOR-swizzled LDS image the proven readA expects.
// B staged 1-tile-ahead via global_load_lds at P1 (Bhi) / P2 (Blo).
// Hazard chains: every producer does waitcnt->barrier before any consumer
// reads (>=1 full barrier between stage-land and cross-wave read).
// ---------------------------------------------------------------------------
#define BM 256
#define BN 256
#define BK 64
#define NT (HID / BK)  // 16 K-tiles

__global__ __launch_bounds__(512, 2) void gemm_k(const float* __restrict__ x,
                                                 const float* __restrict__ gamma,
                                                 const float* __restrict__ beta,
                                                 const float2* __restrict__ stats,
                                                 const bf16* __restrict__ Bt,
                                                 const float* __restrict__ bias,
                                                 float* __restrict__ C) {
    // LDS: [buf(2)][mat(2): A,B][row 256][64 bf16] = 131072 B  + stats/gb
    __shared__ __attribute__((aligned(16))) char lds[131072];
    __shared__ float2 sStats[256];
    __shared__ __attribute__((aligned(16))) float sG[1024];
    __shared__ __attribute__((aligned(16))) float sBe[1024];

    const int tid = threadIdx.x;
    const int w = tid >> 6, ln = tid & 63;
    const int wm = w >> 2, wn = w & 3;
    const int fr = ln & 15, fq = ln >> 4;

    // XCD-chunked bijective swizzle (grid=256, 256%8==0)
    int orig = blockIdx.x;
    int wg = (orig & 7) * 32 + (orig >> 3);
    int bm = wg >> 2, bn = wg & 3;  // 64 x 4 tiles
    const int m0 = bm * BM;

    const bf16* Bb = Bt + (size_t)bn * BN * HID;

    // ---- B staging (unchanged proven gload_lds, mat=B) ----
    auto stageB = [&](int buf, int R0, int kt) {
        char* base = lds + (((buf << 1) | 1) << 15) + (R0 << 7);
        const int kb = kt << 7;
#pragma unroll
        for (int l = 0; l < 2; ++l) {
            int c = (l << 9) + tid;                // chunk 0..1023 (16B)
            int lr = c >> 3;                       // local row 0..127
            int colB = ((c & 7) ^ (lr & 7)) << 4;  // inverse-swizzled src col
            const char* g = (const char*)Bb + (size_t)(R0 + lr) * (HID * 2) + kb + colB;
            __builtin_amdgcn_global_load_lds(
                (const __attribute__((address_space(1))) void*)g,
                (__attribute__((address_space(3))) void*)(base + (((l << 9) + (w << 6)) << 4)),
                16, 0, 0);
        }
    };

    // ---- per-thread A-transform statics: 4 chunks (Alo c, Alo c+512, Ahi...)
    // chunk c=(cc&1)*512+tid: local row rl=(cc&1)*64+(tid>>3) (within half),
    // full row Rf=(cc>>1)*128+rl, src 16B-slot scu=(tid&7)^(rl&7).
    int Rf_[4], scu_[4];
    size_t xoff_[4];
#pragma unroll
    for (int cc = 0; cc < 4; ++cc) {
        int rl = ((cc & 1) << 6) + (tid >> 3);
        int Rf = ((cc >> 1) << 7) + rl;
        int scu = (tid & 7) ^ (rl & 7);
        Rf_[cc] = Rf; scu_[cc] = scu;
        xoff_[cc] = (size_t)(m0 + Rf) * HID + scu * 8;
    }

    // issue next-tile x loads (8 dwordx4) into xr
    auto loadx = [&](int kt, f32x4* xr) {
#pragma unroll
        for (int cc = 0; cc < 4; ++cc) {
            const float* p = x + xoff_[cc] + kt * BK;
            xr[cc * 2]     = *(const f32x4*)p;
            xr[cc * 2 + 1] = *(const f32x4*)(p + 4);
        }
    };

    // LN+sin+bf16 pack, write swizzled LDS image for tile kt into buf
    auto xform = [&](int buf, int kt, f32x4* xr) {
        char* Abase = lds + ((buf << 1) << 15);
#pragma unroll
        for (int cc = 0; cc < 4; ++cc) {
            float2 st = sStats[Rf_[cc]];
            const float mu = st.x, rs = st.y;
            int gb = kt * BK + scu_[cc] * 8;
            float4 g0 = *(const float4*)&sG[gb], g1 = *(const float4*)&sG[gb + 4];
            float4 e0 = *(const float4*)&sBe[gb], e1 = *(const float4*)&sBe[gb + 4];
            f32x4 lo = xr[cc * 2], hi = xr[cc * 2 + 1];
            bf16x8 o;
            o[0] = (bf16)(0.5f * __sinf(2.0f * ((lo[0] - mu) * rs * g0.x + e0.x)));
            o[1] = (bf16)(0.5f * __sinf(2.0f * ((lo[1] - mu) * rs * g0.y + e0.y)));
            o[2] = (bf16)(0.5f * __sinf(2.0f * ((lo[2] - mu) * rs * g0.z + e0.z)));
            o[3] = (bf16)(0.5f * __sinf(2.0f * ((lo[3] - mu) * rs * g0.w + e0.w)));
            o[4] = (bf16)(0.5f * __sinf(2.0f * ((hi[0] - mu) * rs * g1.x + e1.x)));
            o[5] = (bf16)(0.5f * __sinf(2.0f * ((hi[1] - mu) * rs * g1.y + e1.y)));
            o[6] = (bf16)(0.5f * __sinf(2.0f * ((hi[2] - mu) * rs * g1.z + e1.z)));
            o[7] = (bf16)(0.5f * __sinf(2.0f * ((hi[3] - mu) * rs * g1.w + e1.w)));
            char* d = Abase + ((cc >> 1) << 14) + ((((cc & 1) << 9) + tid) << 4);
            *(bf16x8*)d = o;
        }
    };

    // swizzled fragment reads (unchanged)
    auto readA = [&](int buf, int i, int ks) -> bf16x8 {
        int r = ((i * 2 + wm) << 4) + fr;
        int off = (r << 7) + (ks << 6) + (fq << 4);
        off ^= (fr & 7) << 4;
        return *(const bf16x8*)(lds + ((buf << 1) << 15) + off);
    };
    auto readB = [&](int buf, int j, int ks) -> bf16x8 {
        int r = ((j * 4 + wn) << 4) + fr;
        int off = (r << 7) + (ks << 6) + (fq << 4);
        off ^= (fr & 7) << 4;
        return *(const bf16x8*)(lds + (((buf << 1) | 1) << 15) + off);
    };

    f32x4 acc[8][4];
#pragma unroll
    for (int i = 0; i < 8; ++i)
#pragma unroll
        for (int j = 0; j < 4; ++j) acc[i][j] = (f32x4){0.f, 0.f, 0.f, 0.f};

    // ---- prologue ----
    if (tid < 256) sStats[tid] = stats[m0 + tid];
    sG[tid] = gamma[tid];  sG[tid + 512] = gamma[tid + 512];
    sBe[tid] = beta[tid];  sBe[tid + 512] = beta[tid + 512];

    f32x4 xr[8];
    loadx(0, xr);
    stageB(0, 0, 0);     // Blo(0)
    stageB(0, 128, 0);   // Bhi(0)
    asm volatile("s_waitcnt lgkmcnt(0)" ::: "memory");
    __builtin_amdgcn_s_barrier();               // stats/gamma/beta visible
    asm volatile("s_waitcnt vmcnt(0)" ::: "memory");  // xr regs + B(0) landed
    xform(0, 0, xr);
    asm volatile("s_waitcnt lgkmcnt(0)" ::: "memory");
    __builtin_amdgcn_s_barrier();               // A(0) visible

    bf16x8 a[8][2], b[4][2];

#pragma unroll 1
    for (int t = 0; t < NT; ++t) {
        const int cur = t & 1, nxt = cur ^ 1;

        // ---- P0: ds_read Alo+Blo frags; issue x-loads(t+1); MFMA m0-3 x n0-1
#pragma unroll
        for (int i = 0; i < 4; ++i) { a[i][0] = readA(cur, i, 0); a[i][1] = readA(cur, i, 1); }
#pragma unroll
        for (int j = 0; j < 2; ++j) { b[j][0] = readB(cur, j, 0); b[j][1] = readB(cur, j, 1); }
        if (t + 1 < NT) loadx(t + 1, xr);
        __builtin_amdgcn_s_barrier();
        asm volatile("s_waitcnt lgkmcnt(0)" ::: "memory");
        __builtin_amdgcn_sched_barrier(0);
        __builtin_amdgcn_s_setprio(1);
#pragma unroll
        for (int i = 0; i < 4; ++i)
#pragma unroll
            for (int j = 0; j < 2; ++j) {
                acc[i][j] = MFMA(a[i][0], b[j][0], acc[i][j]);
                acc[i][j] = MFMA(a[i][1], b[j][1], acc[i][j]);
            }
        __builtin_amdgcn_s_setprio(0);
        __builtin_amdgcn_s_barrier();

        // ---- P1: ds_read Ahi frags; stage Bhi(t+1)->nxt; MFMA m4-7 x n0-1
#pragma unroll
        for (int i = 4; i < 8; ++i) { a[i][0] = readA(cur, i, 0); a[i][1] = readA(cur, i, 1); }
        if (t + 1 < NT) stageB(nxt, 128, t + 1);
        __builtin_amdgcn_s_barrier();
        asm volatile("s_waitcnt lgkmcnt(0)" ::: "memory");
        __builtin_amdgcn_sched_barrier(0);
        __builtin_amdgcn_s_setprio(1);
#pragma unroll
        for (int i = 4; i < 8; ++i)
#pragma unroll
            for (int j = 0; j < 2; ++j) {
                acc[i][j] = MFMA(a[i][0], b[j][0], acc[i][j]);
                acc[i][j] = MFMA(a[i][1], b[j][1], acc[i][j]);
            }
        __builtin_amdgcn_s_setprio(0);
        __builtin_amdgcn_s_barrier();

        // ---- P2: ds_read Bhi frags; stage Blo(t+1)->nxt; MFMA m4-7 x n2-3
#pragma unroll
        for (int j = 2; j < 4; ++j) { b[j][0] = readB(cur, j, 0); b[j][1] = readB(cur, j, 1); }
        if (t + 1 < NT) stageB(nxt, 0, t + 1);
        __builtin_amdgcn_s_barrier();
        asm volatile("s_waitcnt lgkmcnt(0)" ::: "memory");
        __builtin_amdgcn_sched_barrier(0);
        __builtin_amdgcn_s_setprio(1);
#pragma unroll
        for (int i = 4; i < 8; ++i)
#pragma unroll
            for (int j = 2; j < 4; ++j) {
                acc[i][j] = MFMA(a[i][0], b[j][0], acc[i][j]);
                acc[i][j] = MFMA(a[i][1], b[j][1], acc[i][j]);
            }
        __builtin_amdgcn_s_setprio(0);
        __builtin_amdgcn_s_barrier();

        // ---- P3: MFMA m0-3 x n2-3 (regs only); then drain all vmem
        // (x-loads 3 phases old, Bhi 2, Blo 1 — B from L2-resident Wt),
        // LN+sin transform -> A(t+1) in nxt, drain own ds ops, barrier.
        __builtin_amdgcn_s_setprio(1);
#pragma unroll
        for (int i = 0; i < 4; ++i)
#pragma unroll
            for (int j = 2; j < 4; ++j) {
                acc[i][j] = MFMA(a[i][0], b[j][0], acc[i][j]);
                acc[i][j] = MFMA(a[i][1], b[j][1], acc[i][j]);
            }
        __builtin_amdgcn_s_setprio(0);
        if (t + 1 < NT) {
            asm volatile("s_waitcnt vmcnt(0)" ::: "memory");
            __builtin_amdgcn_sched_barrier(0);
            xform(nxt, t + 1, xr);
            asm volatile("s_waitcnt lgkmcnt(0)" ::: "memory");
        }
        __builtin_amdgcn_sched_barrier(0);
        __builtin_amdgcn_s_barrier();
    }

    // Epilogue: C/D layout col = lane&15, row = (lane>>4)*4 + reg
#pragma unroll
    for (int j = 0; j < 4; ++j) {
        int col = bn * BN + ((j * 4 + wn) << 4) + fr;
        float bv = bias[col];
#pragma unroll
        for (int i = 0; i < 8; ++i) {
            int row0 = bm * BM + ((i * 2 + wm) << 4) + (fq << 2);
#pragma unroll
            for (int jj = 0; jj < 4; ++jj)
                C[(size_t)(row0 + jj) * HID + col] = acc[i][j][jj] + bv;
        }
    }
}

// ---------------------------------------------------------------------------
extern "C" void kernel_launch(void* const* d_in, const int* in_sizes, int n_in,
                              void* d_out, int out_size, void* d_ws, size_t ws_size,
                              hipStream_t stream) {
    const float* x   = (const float*)d_in[0];
    const float* lng = (const float*)d_in[1];
    const float* lnb = (const float*)d_in[2];
    const float* W   = (const float*)d_in[3];
    const float* db  = (const float*)d_in[4];
    float* out = (float*)d_out;

    float2* stats = (float2*)d_ws;                          // 128 KB
    bf16* Wt = (bf16*)((char*)d_ws + (size_t)MROWS * 8);    // 2 MB

    statswt_k<<<256 + MROWS / 8, 256, 0, stream>>>(x, W, stats, Wt);
    gemm_k<<<(MROWS / BM) * (HID / BN), 512, 0, stream>>>(x, lng, lnb, stats, Wt, db, out);
}

// Round 12
// 66.559 us; speedup vs baseline: 1.7567x; 1.7567x over previous
//
#include <hip/hip_runtime.h>
#include <hip/hip_bf16.h>

#define HID 1024
#define MROWS 16384  // B*S = 4*4096

typedef __bf16 bf16;
typedef __bf16 bf16x8 __attribute__((ext_vector_type(8)));
typedef float f32x4 __attribute__((ext_vector_type(4)));

#define MFMA(va, vb, vc) __builtin_amdgcn_mfma_f32_16x16x32_bf16(va, vb, vc, 0, 0, 0)

// ---------------------------------------------------------------------------
// prepwt_k: one launch, 2304 blocks x 256 thr.  (round-8 config: wt FIRST)
//   blocks 0..255    : fold cos-FFT into W -> Wt
//   blocks 256..2303 : LayerNorm + 0.5*sin(2h) -> bf16 A. Wave-per-row,
//                      no LDS/barriers, 4 indep float4 loads/lane,
//                      full-wave shfl_xor reduce, 16B bf16x8 stores.
// ---------------------------------------------------------------------------
__global__ __launch_bounds__(256) void prepwt_k(const float* __restrict__ x,
                                                const float* __restrict__ gamma,
                                                const float* __restrict__ beta,
                                                const float* __restrict__ W,
                                                bf16* __restrict__ A,
                                                bf16* __restrict__ Wt) {
    const int bid = blockIdx.x;
    const int t = threadIdx.x;

    if (bid < 256) {
        // ---- weight fold: Wt[n][q*64+d] = sum_qp ct[(q*qp)&15] * W[qp*64+d][n]
        const int idx = bid * 256 + t;  // 0..65535
        const int n = idx >> 6;
        const int d = idx & 63;

        float wv[16];
#pragma unroll
        for (int qp = 0; qp < 16; ++qp)
            wv[qp] = W[(size_t)(qp * 64 + d) * HID + n];

        const float ct[16] = {
            1.0f,  0.92387953f,  0.70710678f,  0.38268343f,
            0.0f, -0.38268343f, -0.70710678f, -0.92387953f,
           -1.0f, -0.92387953f, -0.70710678f, -0.38268343f,
            0.0f,  0.38268343f,  0.70710678f,  0.92387953f};

#pragma unroll
        for (int q = 0; q < 16; ++q) {
            float acc = 0.0f;
#pragma unroll
            for (int qp = 0; qp < 16; ++qp) acc += wv[qp] * ct[(q * qp) & 15];
            Wt[(size_t)n * HID + q * 64 + d] = (bf16)acc;  // lanes d: coalesced 128B
        }
        return;
    }

    // ---- LN + 0.5*sin(2h): block p handles rows [p*8, p*8+8); wave w rows
    // p*8 + rr*4 + w. Lane ln owns cols [ln*8, ln*8+8) and [512+ln*8, ...+8).
    const int p = bid - 256;
    const int w = t >> 6, ln = t & 63;
    const int c0 = ln * 8;

    float4 ga0 = *(const float4*)&gamma[c0];
    float4 ga1 = *(const float4*)&gamma[c0 + 4];
    float4 ga2 = *(const float4*)&gamma[512 + c0];
    float4 ga3 = *(const float4*)&gamma[512 + c0 + 4];
    float4 be0 = *(const float4*)&beta[c0];
    float4 be1 = *(const float4*)&beta[c0 + 4];
    float4 be2 = *(const float4*)&beta[512 + c0];
    float4 be3 = *(const float4*)&beta[512 + c0 + 4];

#pragma unroll
    for (int rr = 0; rr < 2; ++rr) {
        const int row = p * 8 + rr * 4 + w;
        const float* xr = x + (size_t)row * HID;

        float4 v0 = *(const float4*)&xr[c0];
        float4 v1 = *(const float4*)&xr[c0 + 4];
        float4 v2 = *(const float4*)&xr[512 + c0];
        float4 v3 = *(const float4*)&xr[512 + c0 + 4];

        float s = v0.x + v0.y + v0.z + v0.w + v1.x + v1.y + v1.z + v1.w +
                  v2.x + v2.y + v2.z + v2.w + v3.x + v3.y + v3.z + v3.w;
        float ss = v0.x * v0.x + v0.y * v0.y + v0.z * v0.z + v0.w * v0.w +
                   v1.x * v1.x + v1.y * v1.y + v1.z * v1.z + v1.w * v1.w +
                   v2.x * v2.x + v2.y * v2.y + v2.z * v2.z + v2.w * v2.w +
                   v3.x * v3.x + v3.y * v3.y + v3.z * v3.z + v3.w * v3.w;
#pragma unroll
        for (int off = 32; off; off >>= 1) {
            s  += __shfl_xor(s, off);
            ss += __shfl_xor(ss, off);
        }
        const float mean = s * (1.0f / HID);
        const float rstd = rsqrtf(ss * (1.0f / HID) - mean * mean + 1e-6f);

        float h[16];
        h[0]  = (v0.x - mean) * rstd * ga0.x + be0.x;
        h[1]  = (v0.y - mean) * rstd * ga0.y + be0.y;
        h[2]  = (v0.z - mean) * rstd * ga0.z + be0.z;
        h[3]  = (v0.w - mean) * rstd * ga0.w + be0.w;
        h[4]  = (v1.x - mean) * rstd * ga1.x + be1.x;
        h[5]  = (v1.y - mean) * rstd * ga1.y + be1.y;
        h[6]  = (v1.z - mean) * rstd * ga1.z + be1.z;
        h[7]  = (v1.w - mean) * rstd * ga1.w + be1.w;
        h[8]  = (v2.x - mean) * rstd * ga2.x + be2.x;
        h[9]  = (v2.y - mean) * rstd * ga2.y + be2.y;
        h[10] = (v2.z - mean) * rstd * ga2.z + be2.z;
        h[11] = (v2.w - mean) * rstd * ga2.w + be2.w;
        h[12] = (v3.x - mean) * rstd * ga3.x + be3.x;
        h[13] = (v3.y - mean) * rstd * ga3.y + be3.y;
        h[14] = (v3.z - mean) * rstd * ga3.z + be3.z;
        h[15] = (v3.w - mean) * rstd * ga3.w + be3.w;

        bf16x8 o0, o1;
#pragma unroll
        for (int e = 0; e < 8; ++e) {
            o0[e] = (bf16)(0.5f * __sinf(2.0f * h[e]));
            o1[e] = (bf16)(0.5f * __sinf(2.0f * h[8 + e]));
        }
        *(bf16x8*)&A[(size_t)row * HID + c0] = o0;
        *(bf16x8*)&A[(size_t)row * HID + 512 + c0] = o1;
    }
}

// ---------------------------------------------------------------------------
// Kernel 2: 256x256 8-phase GEMM  C[m][n] = sum_k A[m][k]*Wt[n][k] + bias[n]
// Round-10 best config: proven 8-phase schedule, P3 pre-MFMA barrier removed.
// 8 waves (2M x 4N), BK=64, double-buffered 128 KiB LDS, counted vmcnt,
// XOR-swizzled LDS (inverse-swizzled global source + swizzled ds_read).
// ---------------------------------------------------------------------------
#define BM 256
#define BN 256
#define BK 64
#define NT (HID / BK)  // 16 K-tiles

__global__ __launch_bounds__(512, 2) void gemm_k(const bf16* __restrict__ A,
                                                 const bf16* __restrict__ Bt,
                                                 const float* __restrict__ bias,
                                                 float* __restrict__ C) {
    // LDS: [buf(2)][mat(2): A,B][row 256][64 bf16] = 131072 B
    __shared__ __attribute__((aligned(16))) char lds[131072];

    const int tid = threadIdx.x;
    const int w = tid >> 6, ln = tid & 63;
    const int wm = w >> 2, wn = w & 3;
    const int fr = ln & 15, fq = ln >> 4;

    // XCD-chunked bijective swizzle (grid=256, 256%8==0)
    int orig = blockIdx.x;
    int wg = (orig & 7) * 32 + (orig >> 3);
    int bm = wg >> 2, bn = wg & 3;  // 64 x 4 tiles

    const bf16* Ab = A + (size_t)bm * BM * HID;
    const bf16* Bb = Bt + (size_t)bn * BN * HID;

    auto stage = [&](int buf, int mat, int R0, int kt) {
        const char* gsrc = (const char*)(mat ? Bb : Ab);
        char* base = lds + (((buf << 1) | mat) << 15) + (R0 << 7);
        const int kb = kt << 7;  // kt * 64 cols * 2B
#pragma unroll
        for (int l = 0; l < 2; ++l) {
            int c = (l << 9) + tid;                // chunk 0..1023 (16B each)
            int lr = c >> 3;                       // local row 0..127
            int colB = ((c & 7) ^ (lr & 7)) << 4;  // inverse-swizzled source col
            const char* g = gsrc + (size_t)(R0 + lr) * (HID * 2) + kb + colB;
            __builtin_amdgcn_global_load_lds(
                (const __attribute__((address_space(1))) void*)g,
                (__attribute__((address_space(3))) void*)(base + (((l << 9) + (w << 6)) << 4)),
                16, 0, 0);
        }
    };

    auto readA = [&](int buf, int i, int ks) -> bf16x8 {
        int r = ((i * 2 + wm) << 4) + fr;
        int off = (r << 7) + (ks << 6) + (fq << 4);
        off ^= (fr & 7) << 4;
        return *(const bf16x8*)(lds + ((buf << 1) << 15) + off);
    };
    auto readB = [&](int buf, int j, int ks) -> bf16x8 {
        int r = ((j * 4 + wn) << 4) + fr;
        int off = (r << 7) + (ks << 6) + (fq << 4);
        off ^= (fr & 7) << 4;
        return *(const bf16x8*)(lds + (((buf << 1) | 1) << 15) + off);
    };

    f32x4 acc[8][4];
#pragma unroll
    for (int i = 0; i < 8; ++i)
#pragma unroll
        for (int j = 0; j < 4; ++j) acc[i][j] = (f32x4){0.f, 0.f, 0.f, 0.f};

    // Prologue: Blo(0), Ahi(0), Alo(0), Bhi(0), Blo(1), Ahi(1) -> wait tile 0
    stage(0, 1, 0, 0);
    stage(0, 0, 128, 0);
    stage(0, 0, 0, 0);
    stage(0, 1, 128, 0);
    stage(1, 1, 0, 1);
    stage(1, 0, 128, 1);
    asm volatile("s_waitcnt vmcnt(4)" ::: "memory");
    __builtin_amdgcn_s_barrier();

    bf16x8 a[8][2], b[4][2];

#pragma unroll 1
    for (int t = 0; t < NT; ++t) {
        const int cur = t & 1, nxt = cur ^ 1;

        // ---- P0: ds_read Alo+Blo frags; stage Alo(t+1); MFMA m0-3 x n0-1
#pragma unroll
        for (int i = 0; i < 4; ++i) { a[i][0] = readA(cur, i, 0); a[i][1] = readA(cur, i, 1); }
#pragma unroll
        for (int j = 0; j < 2; ++j) { b[j][0] = readB(cur, j, 0); b[j][1] = readB(cur, j, 1); }
        if (t + 1 < NT) stage(nxt, 0, 0, t + 1);
        __builtin_amdgcn_s_barrier();
        asm volatile("s_waitcnt lgkmcnt(0)" ::: "memory");
        __builtin_amdgcn_sched_barrier(0);
        __builtin_amdgcn_s_setprio(1);
#pragma unroll
        for (int i = 0; i < 4; ++i)
#pragma unroll
            for (int j = 0; j < 2; ++j) {
                acc[i][j] = MFMA(a[i][0], b[j][0], acc[i][j]);
                acc[i][j] = MFMA(a[i][1], b[j][1], acc[i][j]);
            }
        __builtin_amdgcn_s_setprio(0);
        __builtin_amdgcn_s_barrier();

        // ---- P1: ds_read Ahi frags; stage Bhi(t+1); MFMA m4-7 x n0-1
#pragma unroll
        for (int i = 4; i < 8; ++i) { a[i][0] = readA(cur, i, 0); a[i][1] = readA(cur, i, 1); }
        if (t + 1 < NT) stage(nxt, 1, 128, t + 1);
        __builtin_amdgcn_s_barrier();
        asm volatile("s_waitcnt lgkmcnt(0)" ::: "memory");
        __builtin_amdgcn_sched_barrier(0);
        __builtin_amdgcn_s_setprio(1);
#pragma unroll
        for (int i = 4; i < 8; ++i)
#pragma unroll
            for (int j = 0; j < 2; ++j) {
                acc[i][j] = MFMA(a[i][0], b[j][0], acc[i][j]);
                acc[i][j] = MFMA(a[i][1], b[j][1], acc[i][j]);
            }
        __builtin_amdgcn_s_setprio(0);
        __builtin_amdgcn_s_barrier();

        // ---- P2: ds_read Bhi frags; stage Blo(t+2); MFMA m4-7 x n2-3
#pragma unroll
        for (int j = 2; j < 4; ++j) { b[j][0] = readB(cur, j, 0); b[j][1] = readB(cur, j, 1); }
        if (t + 2 < NT) stage(cur, 1, 0, t + 2);
        __builtin_amdgcn_s_barrier();
        asm volatile("s_waitcnt lgkmcnt(0)" ::: "memory");
        __builtin_amdgcn_sched_barrier(0);
        __builtin_amdgcn_s_setprio(1);
#pragma unroll
        for (int i = 4; i < 8; ++i)
#pragma unroll
            for (int j = 2; j < 4; ++j) {
                acc[i][j] = MFMA(a[i][0], b[j][0], acc[i][j]);
                acc[i][j] = MFMA(a[i][1], b[j][1], acc[i][j]);
            }
        __builtin_amdgcn_s_setprio(0);
        __builtin_amdgcn_s_barrier();

        // ---- P3: stage Ahi(t+2); MFMA m0-3 x n2-3 (regs only); counted vmcnt
        if (t + 2 < NT) stage(cur, 0, 128, t + 2);
        __builtin_amdgcn_s_setprio(1);
#pragma unroll
        for (int i = 0; i < 4; ++i)
#pragma unroll
            for (int j = 2; j < 4; ++j) {
                acc[i][j] = MFMA(a[i][0], b[j][0], acc[i][j]);
                acc[i][j] = MFMA(a[i][1], b[j][1], acc[i][j]);
            }
        __builtin_amdgcn_s_setprio(0);
        // wait: all 4 halves of tile t+1 landed; leave tile t+2's in flight
        if (t + 2 < NT) {
            asm volatile("s_waitcnt vmcnt(4)" ::: "memory");
        } else if (t + 1 < NT) {
            asm volatile("s_waitcnt vmcnt(0)" ::: "memory");
        }
        __builtin_amdgcn_sched_barrier(0);
        __builtin_amdgcn_s_barrier();
    }

    // Epilogue: C/D layout col = lane&15, row = (lane>>4)*4 + reg
#pragma unroll
    for (int j = 0; j < 4; ++j) {
        int col = bn * BN + ((j * 4 + wn) << 4) + fr;
        float bv = bias[col];
#pragma unroll
        for (int i = 0; i < 8; ++i) {
            int row0 = bm * BM + ((i * 2 + wm) << 4) + (fq << 2);
#pragma unroll
            for (int jj = 0; jj < 4; ++jj)
                C[(size_t)(row0 + jj) * HID + col] = acc[i][j][jj] + bv;
        }
    }
}

// ---------------------------------------------------------------------------
extern "C" void kernel_launch(void* const* d_in, const int* in_sizes, int n_in,
                              void* d_out, int out_size, void* d_ws, size_t ws_size,
                              hipStream_t stream) {
    const float* x   = (const float*)d_in[0];
    const float* lng = (const float*)d_in[1];
    const float* lnb = (const float*)d_in[2];
    const float* W   = (const float*)d_in[3];
    const float* db  = (const float*)d_in[4];
    float* out = (float*)d_out;

    bf16* A  = (bf16*)d_ws;                                     // 32 MB
    bf16* Wt = (bf16*)((char*)d_ws + (size_t)MROWS * HID * 2);  // 2 MB

    prepwt_k<<<256 + MROWS / 8, 256, 0, stream>>>(x, lng, lnb, W, A, Wt);
    gemm_k<<<(MROWS / BM) * (HID / BN), 512, 0, stream>>>(A, Wt, db, out);
}